// Round 9
// baseline (2393.941 us; speedup 1.0000x reference)
//
#include <hip/hip_runtime.h>
#include <hip/hip_bf16.h>

#define N_FEAT 128
#define HID 16
#define NCLS 10
#define NGRAPH 1024
#define SHIFT 7            // 128 nodes per coarse bin
#define NBMAX 1024         // supports n <= 131072
#define CH 8192            // edges per binning block
#define EPB (CH / 256)     // edges per thread in binning kernels

__device__ __forceinline__ float u2f(unsigned int u) {
    union { unsigned int u; float f; } c; c.u = u; return c.f;
}
__device__ __forceinline__ float bf2f(__hip_bfloat16 b) {
    return __bfloat162float(b);
}
__device__ __forceinline__ unsigned short f2us(float f) {
    union { __hip_bfloat16 b; unsigned short u; } c;
    c.b = __float2bfloat16(f);
    return c.u;
}
__device__ __forceinline__ float ldw(const void* __restrict__ p, int i, int isbf) {
    return isbf ? bf2f(((const __hip_bfloat16*)p)[i]) : ((const float*)p)[i];
}
// unpack 8 bf16 packed in a uint4 into f[0..7]
__device__ __forceinline__ void unp8(uint4 v, float* f) {
    f[0] = u2f(v.x << 16); f[1] = u2f(v.x & 0xffff0000u);
    f[2] = u2f(v.y << 16); f[3] = u2f(v.y & 0xffff0000u);
    f[4] = u2f(v.z << 16); f[5] = u2f(v.z & 0xffff0000u);
    f[6] = u2f(v.w << 16); f[7] = u2f(v.w & 0xffff0000u);
}

// ---------------------------------------------------------------------------
// K0: runtime dtype probes (kept — these made R3 pass).
__global__ void k_detect(const int* __restrict__ ei,
                         const unsigned int* __restrict__ xw,
                         int* __restrict__ flags) {
    if (blockIdx.x == 0 && threadIdx.x == 0) {
        int nz = 0;
        for (int i = 1; i < 256; i += 2) nz |= ei[i];
        flags[0] = (nz == 0) ? 1 : 0;
        int cnt = 0;
        for (int i = 0; i < 64; i++) {
            unsigned int ef = xw[i] & 0x7F80u;
            if (ef >= 0x3C00u && ef <= 0x4080u) cnt++;
        }
        flags[1] = (cnt >= 32) ? 1 : 0;
    }
}

// ---------------------------------------------------------------------------
// K1: h0[i] = emb[argmax(x[i,:])] — one 64-lane wave per node; bf16 output.
__global__ void k_argmax_embed(const void* __restrict__ x,
                               const void* __restrict__ emb,
                               const int* __restrict__ flags,
                               unsigned short* __restrict__ h, int n) {
    int wave = (int)((blockIdx.x * (unsigned)blockDim.x + threadIdx.x) >> 6);
    int lane = threadIdx.x & 63;
    if (wave >= n) return;
    int isbf = flags[1];
    float v0, v1;
    if (isbf) {
        const unsigned int* row =
            (const unsigned int*)((const __hip_bfloat16*)x + (size_t)wave * N_FEAT);
        unsigned int u = row[lane];
        v0 = u2f(u << 16);
        v1 = u2f(u & 0xffff0000u);
    } else {
        const float2* row = (const float2*)((const float*)x + (size_t)wave * N_FEAT);
        float2 u = row[lane];
        v0 = u.x; v1 = u.y;
    }
    float bv; int bi;
    if (v1 > v0) { bv = v1; bi = 2 * lane + 1; }
    else         { bv = v0; bi = 2 * lane; }
    #pragma unroll
    for (int off = 1; off < 64; off <<= 1) {
        float ov = __shfl_xor(bv, off);
        int   oi = __shfl_xor(bi, off);
        if (ov > bv || (ov == bv && oi < bi)) { bv = ov; bi = oi; }
    }
    if (lane < HID) {
        unsigned short us;
        if (isbf) us = ((const unsigned short*)emb)[bi * HID + lane];  // exact copy
        else      us = f2us(((const float*)emb)[bi * HID + lane]);
        h[(size_t)wave * HID + lane] = us;
    }
}

// ---------------------------------------------------------------------------
// K2a: per-block LDS bin histogram -> plain coalesced store of the count row.
__global__ void k_binhist(const int* __restrict__ ei, const int* __restrict__ flags,
                          int* __restrict__ rbBuf, int e, int nbins) {
    __shared__ int lh[NBMAX];
    int t = threadIdx.x;
    for (int b = t; b < nbins; b += 256) lh[b] = 0;
    __syncthreads();
    int base = blockIdx.x * CH;
    int sh = flags[0];
    for (int j = 0; j < EPB; j++) {
        int i = base + j * 256 + t;
        if (i < e) {
            int d = ei[((size_t)(e + i)) << sh];
            atomicAdd(&lh[d >> SHIFT], 1);
        }
    }
    __syncthreads();
    int* row = rbBuf + (size_t)blockIdx.x * nbins;
    for (int b = t; b < nbins; b += 256) row[b] = lh[b];
}

// K2b: per-bin exclusive scan over blocks (in place).
__global__ void k_colscan(int* __restrict__ rbBuf, int* __restrict__ binCnt,
                          int nblk, int nbins) {
    __shared__ int ls[1024];
    int b = blockIdx.x, t = threadIdx.x;
    int v = (t < nblk) ? rbBuf[(size_t)t * nbins + b] : 0;
    ls[t] = v;
    __syncthreads();
    #pragma unroll
    for (int off = 1; off < 1024; off <<= 1) {
        int w = (t >= off) ? ls[t - off] : 0;
        __syncthreads();
        ls[t] += w;
        __syncthreads();
    }
    if (t < nblk) rbBuf[(size_t)t * nbins + b] = ls[t] - v;
    if (t == 1023) binCnt[b] = ls[t];
}

// K2c: exclusive scan of binCnt -> binStart.
__global__ void k_scanbins(const int* __restrict__ binCnt,
                           int* __restrict__ binStart, int nbins, int e) {
    __shared__ int ls[1024];
    int t = threadIdx.x;
    int v = (t < nbins) ? binCnt[t] : 0;
    ls[t] = v;
    __syncthreads();
    #pragma unroll
    for (int off = 1; off < 1024; off <<= 1) {
        int w = (t >= off) ? ls[t - off] : 0;
        __syncthreads();
        ls[t] += w;
        __syncthreads();
    }
    if (t < nbins) binStart[t] = ls[t] - v;
    if (t == 0) binStart[nbins] = e;
}

// K2d: coarse placement, LDS-sorted for coalesced writes (R7 win — kept).
// Output: col[] holds packed (src<<SHIFT | dstLow), grouped by bin.
__global__ __launch_bounds__(256) void k_binplace(
        const int* __restrict__ ei, const int* __restrict__ flags,
        const int* __restrict__ binStart, const int* __restrict__ rbBuf,
        int* __restrict__ col, int e, int nbins) {
    __shared__ int cnt[NBMAX];
    __shared__ int ldsOff[NBMAX];
    __shared__ int ldsBase[NBMAX];
    __shared__ int ps[256];
    __shared__ int stage[CH];
    __shared__ unsigned short binOf[CH];
    int t = threadIdx.x;
    for (int b = t; b < nbins; b += 256) cnt[b] = 0;
    __syncthreads();
    int base = blockIdx.x * CH;
    int sh = flags[0];
    int myV[EPB]; short myB[EPB];
    for (int j = 0; j < EPB; j++) {
        int i = base + j * 256 + t;
        if (i < e) {
            int s = ei[((size_t)i) << sh];
            int d = ei[((size_t)(e + i)) << sh];
            myV[j] = (s << SHIFT) | (d & ((1 << SHIFT) - 1));
            int b2 = d >> SHIFT;
            myB[j] = (short)b2;
            atomicAdd(&cnt[b2], 1);
        } else myB[j] = -1;
    }
    __syncthreads();
    int c[4]; int lsum = 0;
    int bb = t * 4;
    #pragma unroll
    for (int k = 0; k < 4; k++) {
        int b2 = bb + k;
        c[k] = (b2 < nbins) ? cnt[b2] : 0;
        lsum += c[k];
    }
    ps[t] = lsum;
    __syncthreads();
    #pragma unroll
    for (int off = 1; off < 256; off <<= 1) {
        int w = (t >= off) ? ps[t - off] : 0;
        __syncthreads();
        ps[t] += w;
        __syncthreads();
    }
    int run = ps[t] - lsum;
    #pragma unroll
    for (int k = 0; k < 4; k++) {
        int b2 = bb + k;
        if (b2 < nbins) ldsOff[b2] = run;
        run += c[k];
    }
    __syncthreads();
    const int* rb = rbBuf + (size_t)blockIdx.x * nbins;
    for (int b2 = t; b2 < nbins; b2 += 256) {
        ldsBase[b2] = binStart[b2] + rb[b2] - ldsOff[b2];
        cnt[b2] = 0;
    }
    __syncthreads();
    for (int j = 0; j < EPB; j++) {
        if (myB[j] >= 0) {
            int b2 = myB[j];
            int r = atomicAdd(&cnt[b2], 1);
            int p = ldsOff[b2] + r;
            stage[p] = myV[j];
            binOf[p] = (unsigned short)b2;
        }
    }
    __syncthreads();
    int total = e - base;
    if (total > CH) total = CH;
    for (int i = t; i < total; i += 256) {
        int b2 = binOf[i];
        col[ldsBase[b2] + i] = stage[i];
    }
}

// ---------------------------------------------------------------------------
// K3: bin-parallel fused gather + combine, layers 1/2.
// One block per bin (128 nodes). Gather phase: each lane owns one edge —
// coalesced packed-col read, 32B h-row load (L2-resident bf16 table),
// 17 fire-and-forget LDS float atomics into accT[k][node] (+degree row).
// Combine phase: 2 threads per node, weights from LDS, L2-norm, ReLU.
__global__ __launch_bounds__(256) void k_gcbin(
        const int* __restrict__ col, const int* __restrict__ binStart,
        const unsigned short* __restrict__ hin,
        const void* __restrict__ Wl, const void* __restrict__ bia,
        const void* __restrict__ Wr, const int* __restrict__ flags,
        unsigned short* __restrict__ hout, int n) {
    __shared__ float accT[HID + 1][1 << SHIFT];   // [k][node], row 16 = degree
    __shared__ float wl[HID][HID], wr[HID][HID], bb[HID];
    int t = threadIdx.x;
    int b = blockIdx.x;
    int isbf = flags[1];
    if (t < HID * HID) {
        wl[t >> 4][t & 15] = ldw(Wl, t, isbf);
        wr[t >> 4][t & 15] = ldw(Wr, t, isbf);
    }
    if (t < HID) bb[t] = ldw(bia, t, isbf);
    for (int i = t; i < (HID + 1) * (1 << SHIFT); i += 256)
        ((float*)accT)[i] = 0.0f;
    __syncthreads();
    int s0 = binStart[b], s1 = binStart[b + 1];
    const uint4* h4 = (const uint4*)hin;
    for (int i = s0 + t; i < s1; i += 256) {
        int v = __builtin_nontemporal_load(col + i);
        int s = v >> SHIFT;
        int dl = v & ((1 << SHIFT) - 1);
        uint4 u0 = h4[(size_t)s * 2];
        uint4 u1 = h4[(size_t)s * 2 + 1];
        float f0[8], f1[8];
        unp8(u0, f0); unp8(u1, f1);
        #pragma unroll
        for (int k = 0; k < 8; k++) atomicAdd(&accT[k][dl], f0[k]);
        #pragma unroll
        for (int k = 0; k < 8; k++) atomicAdd(&accT[8 + k][dl], f1[k]);
        atomicAdd(&accT[HID][dl], 1.0f);
    }
    __syncthreads();
    int ln = t >> 1;
    int node = (b << SHIFT) + ln;
    if (node >= n) return;
    int half = t & 1;
    float invd = 1.0f / fmaxf(accT[HID][ln], 1.0f);
    float a[HID], hb[HID];
    #pragma unroll
    for (int k = 0; k < HID; k++) a[k] = accT[k][ln] * invd;
    uint4 s0v = h4[(size_t)node * 2];
    uint4 s1v = h4[(size_t)node * 2 + 1];
    unp8(s0v, hb); unp8(s1v, hb + 8);
    float o[8]; float sq = 0.0f;
    #pragma unroll
    for (int j = 0; j < 8; j++) {
        int f = half * 8 + j;
        float acc = bb[f];
        #pragma unroll
        for (int k = 0; k < HID; k++)
            acc += a[k] * wl[f][k] + hb[k] * wr[f][k];
        o[j] = acc;
        sq += acc * acc;
    }
    sq += __shfl_xor(sq, 1);
    float innorm = 1.0f / fmaxf(sqrtf(sq), 1e-12f);
    uint4 w;
    unsigned int* wp = (unsigned int*)&w;
    #pragma unroll
    for (int j = 0; j < 4; j++) {
        unsigned int lo = f2us(fmaxf(o[2 * j] * innorm, 0.0f));
        unsigned int hi = f2us(fmaxf(o[2 * j + 1] * innorm, 0.0f));
        wp[j] = lo | (hi << 16);
    }
    ((uint4*)hout)[(size_t)node * 2 + half] = w;
}

// K4: layer-3 variant — 10 outputs (zero-padded rows), no ReLU, fp32 h3.
__global__ __launch_bounds__(256) void k_gcbin3(
        const int* __restrict__ col, const int* __restrict__ binStart,
        const unsigned short* __restrict__ hin,
        const void* __restrict__ Wl, const void* __restrict__ bia,
        const void* __restrict__ Wr, const int* __restrict__ flags,
        float* __restrict__ h3, int n) {
    __shared__ float accT[HID + 1][1 << SHIFT];
    __shared__ float wl[HID][HID], wr[HID][HID], bb[HID];
    int t = threadIdx.x;
    int b = blockIdx.x;
    int isbf = flags[1];
    if (t < HID * HID) {
        int r = t >> 4, c = t & 15;
        wl[r][c] = (r < NCLS) ? ldw(Wl, r * HID + c, isbf) : 0.0f;
        wr[r][c] = (r < NCLS) ? ldw(Wr, r * HID + c, isbf) : 0.0f;
    }
    if (t < HID) bb[t] = (t < NCLS) ? ldw(bia, t, isbf) : 0.0f;
    for (int i = t; i < (HID + 1) * (1 << SHIFT); i += 256)
        ((float*)accT)[i] = 0.0f;
    __syncthreads();
    int s0 = binStart[b], s1 = binStart[b + 1];
    const uint4* h4 = (const uint4*)hin;
    for (int i = s0 + t; i < s1; i += 256) {
        int v = __builtin_nontemporal_load(col + i);
        int s = v >> SHIFT;
        int dl = v & ((1 << SHIFT) - 1);
        uint4 u0 = h4[(size_t)s * 2];
        uint4 u1 = h4[(size_t)s * 2 + 1];
        float f0[8], f1[8];
        unp8(u0, f0); unp8(u1, f1);
        #pragma unroll
        for (int k = 0; k < 8; k++) atomicAdd(&accT[k][dl], f0[k]);
        #pragma unroll
        for (int k = 0; k < 8; k++) atomicAdd(&accT[8 + k][dl], f1[k]);
        atomicAdd(&accT[HID][dl], 1.0f);
    }
    __syncthreads();
    int ln = t >> 1;
    int node = (b << SHIFT) + ln;
    if (node >= n) return;
    int half = t & 1;
    float invd = 1.0f / fmaxf(accT[HID][ln], 1.0f);
    float a[HID], hb[HID];
    #pragma unroll
    for (int k = 0; k < HID; k++) a[k] = accT[k][ln] * invd;
    uint4 s0v = h4[(size_t)node * 2];
    uint4 s1v = h4[(size_t)node * 2 + 1];
    unp8(s0v, hb); unp8(s1v, hb + 8);
    float o[8]; float sq = 0.0f;
    #pragma unroll
    for (int j = 0; j < 8; j++) {
        int f = half * 8 + j;
        float acc = bb[f];
        #pragma unroll
        for (int k = 0; k < HID; k++)
            acc += a[k] * wl[f][k] + hb[k] * wr[f][k];
        o[j] = acc;               // rows >= NCLS give 0
        sq += acc * acc;
    }
    sq += __shfl_xor(sq, 1);
    float innorm = 1.0f / fmaxf(sqrtf(sq), 1e-12f);
    float* op = h3 + (size_t)node * NCLS;
    if (half == 0) {
        #pragma unroll
        for (int j = 0; j < 8; j++) op[j] = o[j] * innorm;
    } else {
        op[8] = o[0] * innorm;
        op[9] = o[1] * innorm;
    }
}

// ---------------------------------------------------------------------------
// K5: per-graph mean pool (batch sorted -> binary search) + softmax.
__device__ __forceinline__ int lbound(const int* __restrict__ a, int n, int key, int sh) {
    int lo = 0, hi = n;
    while (lo < hi) {
        int mid = (lo + hi) >> 1;
        if (a[((size_t)mid) << sh] < key) lo = mid + 1; else hi = mid;
    }
    return lo;
}

__global__ void k_pool_softmax(const float* __restrict__ h3,
                               const int* __restrict__ batch,
                               const int* __restrict__ flags,
                               void* __restrict__ out, int n) {
    int g = blockIdx.x;
    int lane = threadIdx.x;
    int sh = flags[0];
    int lo = lbound(batch, n, g, sh);
    int hi = lbound(batch, n, g + 1, sh);
    float acc[NCLS];
    #pragma unroll
    for (int c = 0; c < NCLS; c++) acc[c] = 0.0f;
    for (int i = lo + lane; i < hi; i += 64) {
        const float* r = h3 + (size_t)i * NCLS;
        #pragma unroll
        for (int c = 0; c < NCLS; c++) acc[c] += r[c];
    }
    #pragma unroll
    for (int c = 0; c < NCLS; c++) {
        #pragma unroll
        for (int off = 1; off < 64; off <<= 1)
            acc[c] += __shfl_xor(acc[c], off);
    }
    float invc = 1.0f / fmaxf((float)(hi - lo), 1.0f);
    float m = -1e30f;
    #pragma unroll
    for (int c = 0; c < NCLS; c++) { acc[c] *= invc; m = fmaxf(m, acc[c]); }
    float s = 0.0f;
    #pragma unroll
    for (int c = 0; c < NCLS; c++) { acc[c] = expf(acc[c] - m); s += acc[c]; }
    float invs = 1.0f / s;
    if (lane < NCLS) {
        float v = acc[lane] * invs;
        size_t idx = (size_t)g * NCLS + lane;
        if (flags[1]) ((__hip_bfloat16*)out)[idx] = __float2bfloat16(v);
        else          ((float*)out)[idx] = v;
    }
}

// ---------------------------------------------------------------------------
extern "C" void kernel_launch(void* const* d_in, const int* in_sizes, int n_in,
                              void* d_out, int out_size, void* d_ws, size_t ws_size,
                              hipStream_t stream) {
    const void* x   = d_in[0];
    const int*  ei  = (const int*)d_in[1];
    const int*  bat = (const int*)d_in[2];
    const void* emb = d_in[3];
    const void* W1l = d_in[4];  const void* b1 = d_in[5];  const void* W1r = d_in[6];
    const void* W2l = d_in[7];  const void* b2 = d_in[8];  const void* W2r = d_in[9];
    const void* W3l = d_in[10]; const void* b3 = d_in[11]; const void* W3r = d_in[12];

    int n = in_sizes[0] / N_FEAT;
    int e = in_sizes[1] / 2;
    int nbins = (n + (1 << SHIFT) - 1) >> SHIFT;
    int nblk  = (e + CH - 1) / CH;

    // ws: hcur[16n] bf16 | hnext[16n] bf16 | h3[10n] f32 | col[e] |
    //     binCnt[nbins] | binStart[nbins+1] | rbBuf[nblk*nbins] | flags[2]
    unsigned short* hcur  = (unsigned short*)d_ws;
    unsigned short* hnext = hcur + (size_t)n * HID;
    float* h3       = (float*)(hnext + (size_t)n * HID);
    int*   col      = (int*)(h3 + (size_t)n * NCLS);
    int*   binCnt   = col + e;
    int*   binStart = binCnt + nbins;
    int*   rbBuf    = binStart + (nbins + 1);
    int*   flags    = rbBuf + (size_t)nblk * nbins;

    int ngrid4 = (n + 3) / 4;

    // probes + binned edge build (packed (src<<7|dstLow), bin-grouped)
    k_detect<<<1, 64, 0, stream>>>(ei, (const unsigned int*)x, flags);
    k_binhist<<<nblk, 256, 0, stream>>>(ei, flags, rbBuf, e, nbins);
    k_colscan<<<nbins, 1024, 0, stream>>>(rbBuf, binCnt, nblk, nbins);
    k_scanbins<<<1, 1024, 0, stream>>>(binCnt, binStart, nbins, e);
    k_binplace<<<nblk, 256, 0, stream>>>(ei, flags, binStart, rbBuf, col, e, nbins);

    // initial embedding (bf16 h table)
    k_argmax_embed<<<ngrid4, 256, 0, stream>>>(x, emb, flags, hcur, n);

    // 3 bin-parallel gather+combine layers (LDS-atomic accumulation)
    k_gcbin <<<nbins, 256, 0, stream>>>(col, binStart, hcur,  W1l, b1, W1r, flags, hnext, n);
    k_gcbin <<<nbins, 256, 0, stream>>>(col, binStart, hnext, W2l, b2, W2r, flags, hcur,  n);
    k_gcbin3<<<nbins, 256, 0, stream>>>(col, binStart, hcur,  W3l, b3, W3r, flags, h3,    n);

    // pool + softmax
    k_pool_softmax<<<NGRAPH, 64, 0, stream>>>(h3, bat, flags, d_out, n);
}

// Round 10
// 775.076 us; speedup vs baseline: 3.0887x; 3.0887x over previous
//
#include <hip/hip_runtime.h>
#include <hip/hip_bf16.h>

#define N_FEAT 128
#define HID 16
#define NCLS 10
#define NGRAPH 1024
#define SHIFT 7            // 128 nodes per coarse bin
#define NBMAX 1024         // supports n <= 131072
#define CAP 24576          // LDS staging entries in k_place (96 KB)
#define CH 8192            // edges per binning block
#define EPB (CH / 256)     // edges per thread in binning kernels

__device__ __forceinline__ float u2f(unsigned int u) {
    union { unsigned int u; float f; } c; c.u = u; return c.f;
}
__device__ __forceinline__ float bf2f(__hip_bfloat16 b) {
    return __bfloat162float(b);
}
__device__ __forceinline__ unsigned short f2us(float f) {
    union { __hip_bfloat16 b; unsigned short u; } c;
    c.b = __float2bfloat16(f);
    return c.u;
}
__device__ __forceinline__ float ldw(const void* __restrict__ p, int i, int isbf) {
    return isbf ? bf2f(((const __hip_bfloat16*)p)[i]) : ((const float*)p)[i];
}
// unpack 8 bf16 packed in a uint4 into f[0..7]
__device__ __forceinline__ void unp8(uint4 v, float* f) {
    f[0] = u2f(v.x << 16); f[1] = u2f(v.x & 0xffff0000u);
    f[2] = u2f(v.y << 16); f[3] = u2f(v.y & 0xffff0000u);
    f[4] = u2f(v.z << 16); f[5] = u2f(v.z & 0xffff0000u);
    f[6] = u2f(v.w << 16); f[7] = u2f(v.w & 0xffff0000u);
}

// ---------------------------------------------------------------------------
// K0: runtime dtype probes (kept — these made R3 pass).
__global__ void k_detect(const int* __restrict__ ei,
                         const unsigned int* __restrict__ xw,
                         int* __restrict__ flags) {
    if (blockIdx.x == 0 && threadIdx.x == 0) {
        int nz = 0;
        for (int i = 1; i < 256; i += 2) nz |= ei[i];
        flags[0] = (nz == 0) ? 1 : 0;
        int cnt = 0;
        for (int i = 0; i < 64; i++) {
            unsigned int ef = xw[i] & 0x7F80u;
            if (ef >= 0x3C00u && ef <= 0x4080u) cnt++;
        }
        flags[1] = (cnt >= 32) ? 1 : 0;
    }
}

// ---------------------------------------------------------------------------
// K1: h0[i] = emb[argmax(x[i,:])] — one 64-lane wave per node; bf16 output.
__global__ void k_argmax_embed(const void* __restrict__ x,
                               const void* __restrict__ emb,
                               const int* __restrict__ flags,
                               unsigned short* __restrict__ h, int n) {
    int wave = (int)((blockIdx.x * (unsigned)blockDim.x + threadIdx.x) >> 6);
    int lane = threadIdx.x & 63;
    if (wave >= n) return;
    int isbf = flags[1];
    float v0, v1;
    if (isbf) {
        const unsigned int* row =
            (const unsigned int*)((const __hip_bfloat16*)x + (size_t)wave * N_FEAT);
        unsigned int u = row[lane];
        v0 = u2f(u << 16);
        v1 = u2f(u & 0xffff0000u);
    } else {
        const float2* row = (const float2*)((const float*)x + (size_t)wave * N_FEAT);
        float2 u = row[lane];
        v0 = u.x; v1 = u.y;
    }
    float bv; int bi;
    if (v1 > v0) { bv = v1; bi = 2 * lane + 1; }
    else         { bv = v0; bi = 2 * lane; }
    #pragma unroll
    for (int off = 1; off < 64; off <<= 1) {
        float ov = __shfl_xor(bv, off);
        int   oi = __shfl_xor(bi, off);
        if (ov > bv || (ov == bv && oi < bi)) { bv = ov; bi = oi; }
    }
    if (lane < HID) {
        unsigned short us;
        if (isbf) us = ((const unsigned short*)emb)[bi * HID + lane];  // exact copy
        else      us = f2us(((const float*)emb)[bi * HID + lane]);
        h[(size_t)wave * HID + lane] = us;
    }
}

// ---------------------------------------------------------------------------
// K2a: per-block LDS bin histogram -> plain coalesced store of the count row.
__global__ void k_binhist(const int* __restrict__ ei, const int* __restrict__ flags,
                          int* __restrict__ rbBuf, int e, int nbins) {
    __shared__ int lh[NBMAX];
    int t = threadIdx.x;
    for (int b = t; b < nbins; b += 256) lh[b] = 0;
    __syncthreads();
    int base = blockIdx.x * CH;
    int sh = flags[0];
    for (int j = 0; j < EPB; j++) {
        int i = base + j * 256 + t;
        if (i < e) {
            int d = ei[((size_t)(e + i)) << sh];
            atomicAdd(&lh[d >> SHIFT], 1);
        }
    }
    __syncthreads();
    int* row = rbBuf + (size_t)blockIdx.x * nbins;
    for (int b = t; b < nbins; b += 256) row[b] = lh[b];
}

// K2b: per-bin exclusive scan over blocks (in place).
__global__ void k_colscan(int* __restrict__ rbBuf, int* __restrict__ binCnt,
                          int nblk, int nbins) {
    __shared__ int ls[1024];
    int b = blockIdx.x, t = threadIdx.x;
    int v = (t < nblk) ? rbBuf[(size_t)t * nbins + b] : 0;
    ls[t] = v;
    __syncthreads();
    #pragma unroll
    for (int off = 1; off < 1024; off <<= 1) {
        int w = (t >= off) ? ls[t - off] : 0;
        __syncthreads();
        ls[t] += w;
        __syncthreads();
    }
    if (t < nblk) rbBuf[(size_t)t * nbins + b] = ls[t] - v;
    if (t == 1023) binCnt[b] = ls[t];
}

// K2c: exclusive scan of binCnt -> binStart.
__global__ void k_scanbins(const int* __restrict__ binCnt,
                           int* __restrict__ binStart, int nbins, int e) {
    __shared__ int ls[1024];
    int t = threadIdx.x;
    int v = (t < nbins) ? binCnt[t] : 0;
    ls[t] = v;
    __syncthreads();
    #pragma unroll
    for (int off = 1; off < 1024; off <<= 1) {
        int w = (t >= off) ? ls[t - off] : 0;
        __syncthreads();
        ls[t] += w;
        __syncthreads();
    }
    if (t < nbins) binStart[t] = ls[t] - v;
    if (t == 0) binStart[nbins] = e;
}

// K2d: coarse placement, LDS-sorted for coalesced writes (R7 win — kept).
__global__ __launch_bounds__(256) void k_binplace(
        const int* __restrict__ ei, const int* __restrict__ flags,
        const int* __restrict__ binStart, const int* __restrict__ rbBuf,
        int* __restrict__ col, int e, int nbins) {
    __shared__ int cnt[NBMAX];
    __shared__ int ldsOff[NBMAX];
    __shared__ int ldsBase[NBMAX];
    __shared__ int ps[256];
    __shared__ int stage[CH];
    __shared__ unsigned short binOf[CH];
    int t = threadIdx.x;
    for (int b = t; b < nbins; b += 256) cnt[b] = 0;
    __syncthreads();
    int base = blockIdx.x * CH;
    int sh = flags[0];
    int myV[EPB]; short myB[EPB];
    for (int j = 0; j < EPB; j++) {
        int i = base + j * 256 + t;
        if (i < e) {
            int s = ei[((size_t)i) << sh];
            int d = ei[((size_t)(e + i)) << sh];
            myV[j] = (s << SHIFT) | (d & ((1 << SHIFT) - 1));
            int b2 = d >> SHIFT;
            myB[j] = (short)b2;
            atomicAdd(&cnt[b2], 1);
        } else myB[j] = -1;
    }
    __syncthreads();
    int c[4]; int lsum = 0;
    int bb = t * 4;
    #pragma unroll
    for (int k = 0; k < 4; k++) {
        int b2 = bb + k;
        c[k] = (b2 < nbins) ? cnt[b2] : 0;
        lsum += c[k];
    }
    ps[t] = lsum;
    __syncthreads();
    #pragma unroll
    for (int off = 1; off < 256; off <<= 1) {
        int w = (t >= off) ? ps[t - off] : 0;
        __syncthreads();
        ps[t] += w;
        __syncthreads();
    }
    int run = ps[t] - lsum;
    #pragma unroll
    for (int k = 0; k < 4; k++) {
        int b2 = bb + k;
        if (b2 < nbins) ldsOff[b2] = run;
        run += c[k];
    }
    __syncthreads();
    const int* rb = rbBuf + (size_t)blockIdx.x * nbins;
    for (int b2 = t; b2 < nbins; b2 += 256) {
        ldsBase[b2] = binStart[b2] + rb[b2] - ldsOff[b2];
        cnt[b2] = 0;
    }
    __syncthreads();
    for (int j = 0; j < EPB; j++) {
        if (myB[j] >= 0) {
            int b2 = myB[j];
            int r = atomicAdd(&cnt[b2], 1);
            int p = ldsOff[b2] + r;
            stage[p] = myV[j];
            binOf[p] = (unsigned short)b2;
        }
    }
    __syncthreads();
    int total = e - base;
    if (total > CH) total = CH;
    for (int i = t; i < total; i += 256) {
        int b2 = binOf[i];
        col[ldsBase[b2] + i] = stage[i];
    }
}

// K2e: fine placement + per-node rowStart (R8 version — restored).
__global__ void k_place(int* __restrict__ col, const int* __restrict__ binStart,
                        int* __restrict__ rowStart, int n, int e) {
    __shared__ int stage[CAP];
    __shared__ int cntN[1 << SHIFT];
    __shared__ int sc[1 << SHIFT];
    __shared__ int rs[1 << SHIFT];
    int b = blockIdx.x;
    int t = threadIdx.x;
    int nb = b << SHIFT;
    int s0 = binStart[b];
    int s1 = binStart[b + 1];
    int cnt = s1 - s0;
    if (t < (1 << SHIFT)) cntN[t] = 0;
    bool st = (cnt <= CAP);
    __syncthreads();
    for (int i = t; i < cnt; i += 256) {
        int v = col[s0 + i];
        if (st) stage[i] = v;
        atomicAdd(&cntN[v & ((1 << SHIFT) - 1)], 1);
    }
    __syncthreads();
    if (t < (1 << SHIFT)) sc[t] = cntN[t];
    __syncthreads();
    #pragma unroll
    for (int off = 1; off < (1 << SHIFT); off <<= 1) {
        int w = 0;
        if (t < (1 << SHIFT) && t >= off) w = sc[t - off];
        __syncthreads();
        if (t < (1 << SHIFT)) sc[t] += w;
        __syncthreads();
    }
    if (t < (1 << SHIFT)) {
        int start = s0 + sc[t] - cntN[t];
        rs[t] = start;
        int node = nb + t;
        if (node < n) rowStart[node] = start;
        cntN[t] = 0;
    }
    __syncthreads();
    for (int i = t; i < cnt; i += 256) {
        int v = st ? stage[i] : col[s0 + i];
        int dl = v & ((1 << SHIFT) - 1);
        int r = atomicAdd(&cntN[dl], 1);
        col[rs[dl] + r] = v >> SHIFT;
    }
}

// ---------------------------------------------------------------------------
// K3: THREAD-per-node fused gather + combine, layers 1/2.
// No shfls (shfl = ds_bpermute = DS-pipe, the R8/R9 bottleneck). Each thread:
// sequential independent 2xuint4 row loads (L2-resident bf16 table), fp32
// register accumulate, full 16x16 matmul with wave-uniform (broadcast) LDS
// weight reads, L2-norm, ReLU, packed 32B store.
__global__ __launch_bounds__(256) void k_gc(
        const int* __restrict__ col, const int* __restrict__ rowStart,
        const unsigned short* __restrict__ hin,
        const void* __restrict__ Wl, const void* __restrict__ bia,
        const void* __restrict__ Wr, const int* __restrict__ flags,
        unsigned short* __restrict__ hout, int n, int e) {
    __shared__ float wl[HID][HID], wr[HID][HID], bb[HID];
    int t = threadIdx.x;
    int isbf = flags[1];
    if (t < HID * HID) {
        wl[t >> 4][t & 15] = ldw(Wl, t, isbf);
        wr[t >> 4][t & 15] = ldw(Wr, t, isbf);
    }
    if (t < HID) bb[t] = ldw(bia, t, isbf);
    __syncthreads();
    int node = blockIdx.x * 256 + t;
    if (node >= n) return;
    int lo = rowStart[node];
    int hi = (node + 1 < n) ? rowStart[node + 1] : e;
    const uint4* h4 = (const uint4*)hin;
    float a[HID];
    #pragma unroll
    for (int k = 0; k < HID; k++) a[k] = 0.0f;
    for (int i = lo; i < hi; i++) {
        int s = __builtin_nontemporal_load(col + i);
        uint4 u0 = h4[(size_t)s * 2];
        uint4 u1 = h4[(size_t)s * 2 + 1];
        float f0[8], f1[8];
        unp8(u0, f0); unp8(u1, f1);
        #pragma unroll
        for (int k = 0; k < 8; k++) { a[k] += f0[k]; a[8 + k] += f1[k]; }
    }
    float invd = 1.0f / fmaxf((float)(hi - lo), 1.0f);
    #pragma unroll
    for (int k = 0; k < HID; k++) a[k] *= invd;
    float hb[HID];
    unp8(h4[(size_t)node * 2], hb);
    unp8(h4[(size_t)node * 2 + 1], hb + 8);
    float o[HID]; float sq = 0.0f;
    #pragma unroll
    for (int f = 0; f < HID; f++) {
        float acc = bb[f];
        #pragma unroll
        for (int k = 0; k < HID; k++)
            acc += a[k] * wl[f][k] + hb[k] * wr[f][k];
        o[f] = acc;
        sq += acc * acc;
    }
    float inn = 1.0f / fmaxf(sqrtf(sq), 1e-12f);
    uint4 w0, w1;
    unsigned int* wp0 = (unsigned int*)&w0;
    unsigned int* wp1 = (unsigned int*)&w1;
    #pragma unroll
    for (int j = 0; j < 4; j++) {
        unsigned int l0 = f2us(fmaxf(o[2 * j] * inn, 0.0f));
        unsigned int h0 = f2us(fmaxf(o[2 * j + 1] * inn, 0.0f));
        wp0[j] = l0 | (h0 << 16);
        unsigned int l1 = f2us(fmaxf(o[8 + 2 * j] * inn, 0.0f));
        unsigned int h1 = f2us(fmaxf(o[8 + 2 * j + 1] * inn, 0.0f));
        wp1[j] = l1 | (h1 << 16);
    }
    ((uint4*)hout)[(size_t)node * 2]     = w0;
    ((uint4*)hout)[(size_t)node * 2 + 1] = w1;
}

// K4: thread-per-node layer 3 (10 outputs, no ReLU, fp32 h3).
__global__ __launch_bounds__(256) void k_gc3(
        const int* __restrict__ col, const int* __restrict__ rowStart,
        const unsigned short* __restrict__ hin,
        const void* __restrict__ Wl, const void* __restrict__ bia,
        const void* __restrict__ Wr, const int* __restrict__ flags,
        float* __restrict__ h3, int n, int e) {
    __shared__ float wl[NCLS][HID], wr[NCLS][HID], bb[NCLS];
    int t = threadIdx.x;
    int isbf = flags[1];
    if (t < NCLS * HID) {
        wl[t >> 4][t & 15] = ldw(Wl, t, isbf);
        wr[t >> 4][t & 15] = ldw(Wr, t, isbf);
    }
    if (t < NCLS) bb[t] = ldw(bia, t, isbf);
    __syncthreads();
    int node = blockIdx.x * 256 + t;
    if (node >= n) return;
    int lo = rowStart[node];
    int hi = (node + 1 < n) ? rowStart[node + 1] : e;
    const uint4* h4 = (const uint4*)hin;
    float a[HID];
    #pragma unroll
    for (int k = 0; k < HID; k++) a[k] = 0.0f;
    for (int i = lo; i < hi; i++) {
        int s = __builtin_nontemporal_load(col + i);
        uint4 u0 = h4[(size_t)s * 2];
        uint4 u1 = h4[(size_t)s * 2 + 1];
        float f0[8], f1[8];
        unp8(u0, f0); unp8(u1, f1);
        #pragma unroll
        for (int k = 0; k < 8; k++) { a[k] += f0[k]; a[8 + k] += f1[k]; }
    }
    float invd = 1.0f / fmaxf((float)(hi - lo), 1.0f);
    #pragma unroll
    for (int k = 0; k < HID; k++) a[k] *= invd;
    float hb[HID];
    unp8(h4[(size_t)node * 2], hb);
    unp8(h4[(size_t)node * 2 + 1], hb + 8);
    float o[NCLS]; float sq = 0.0f;
    #pragma unroll
    for (int f = 0; f < NCLS; f++) {
        float acc = bb[f];
        #pragma unroll
        for (int k = 0; k < HID; k++)
            acc += a[k] * wl[f][k] + hb[k] * wr[f][k];
        o[f] = acc;
        sq += acc * acc;
    }
    float inn = 1.0f / fmaxf(sqrtf(sq), 1e-12f);
    float* op = h3 + (size_t)node * NCLS;
    #pragma unroll
    for (int f = 0; f < NCLS; f++) op[f] = o[f] * inn;
}

// ---------------------------------------------------------------------------
// K5: per-graph mean pool (batch sorted -> binary search) + softmax.
__device__ __forceinline__ int lbound(const int* __restrict__ a, int n, int key, int sh) {
    int lo = 0, hi = n;
    while (lo < hi) {
        int mid = (lo + hi) >> 1;
        if (a[((size_t)mid) << sh] < key) lo = mid + 1; else hi = mid;
    }
    return lo;
}

__global__ void k_pool_softmax(const float* __restrict__ h3,
                               const int* __restrict__ batch,
                               const int* __restrict__ flags,
                               void* __restrict__ out, int n) {
    int g = blockIdx.x;
    int lane = threadIdx.x;
    int sh = flags[0];
    int lo = lbound(batch, n, g, sh);
    int hi = lbound(batch, n, g + 1, sh);
    float acc[NCLS];
    #pragma unroll
    for (int c = 0; c < NCLS; c++) acc[c] = 0.0f;
    for (int i = lo + lane; i < hi; i += 64) {
        const float* r = h3 + (size_t)i * NCLS;
        #pragma unroll
        for (int c = 0; c < NCLS; c++) acc[c] += r[c];
    }
    #pragma unroll
    for (int c = 0; c < NCLS; c++) {
        #pragma unroll
        for (int off = 1; off < 64; off <<= 1)
            acc[c] += __shfl_xor(acc[c], off);
    }
    float invc = 1.0f / fmaxf((float)(hi - lo), 1.0f);
    float m = -1e30f;
    #pragma unroll
    for (int c = 0; c < NCLS; c++) { acc[c] *= invc; m = fmaxf(m, acc[c]); }
    float s = 0.0f;
    #pragma unroll
    for (int c = 0; c < NCLS; c++) { acc[c] = expf(acc[c] - m); s += acc[c]; }
    float invs = 1.0f / s;
    if (lane < NCLS) {
        float v = acc[lane] * invs;
        size_t idx = (size_t)g * NCLS + lane;
        if (flags[1]) ((__hip_bfloat16*)out)[idx] = __float2bfloat16(v);
        else          ((float*)out)[idx] = v;
    }
}

// ---------------------------------------------------------------------------
extern "C" void kernel_launch(void* const* d_in, const int* in_sizes, int n_in,
                              void* d_out, int out_size, void* d_ws, size_t ws_size,
                              hipStream_t stream) {
    const void* x   = d_in[0];
    const int*  ei  = (const int*)d_in[1];
    const int*  bat = (const int*)d_in[2];
    const void* emb = d_in[3];
    const void* W1l = d_in[4];  const void* b1 = d_in[5];  const void* W1r = d_in[6];
    const void* W2l = d_in[7];  const void* b2 = d_in[8];  const void* W2r = d_in[9];
    const void* W3l = d_in[10]; const void* b3 = d_in[11]; const void* W3r = d_in[12];

    int n = in_sizes[0] / N_FEAT;
    int e = in_sizes[1] / 2;
    int nbins = (n + (1 << SHIFT) - 1) >> SHIFT;
    int nblk  = (e + CH - 1) / CH;

    // ws: hcur[16n] bf16 | hnext[16n] bf16 | h3[10n] f32 | col[e] |
    //     rowStart[n] | binCnt | binStart | rbBuf[nblk*nbins] | flags
    unsigned short* hcur  = (unsigned short*)d_ws;
    unsigned short* hnext = hcur + (size_t)n * HID;
    float* h3       = (float*)(hnext + (size_t)n * HID);
    int*   col      = (int*)(h3 + (size_t)n * NCLS);
    int*   rowStart = col + e;
    int*   binCnt   = rowStart + n;
    int*   binStart = binCnt + nbins;
    int*   rbBuf    = binStart + (nbins + 1);
    int*   flags    = rbBuf + (size_t)nblk * nbins;

    int ngrid4 = (n + 3) / 4;
    int ngrid256 = (n + 255) / 256;

    // probes + CSR build
    k_detect<<<1, 64, 0, stream>>>(ei, (const unsigned int*)x, flags);
    k_binhist<<<nblk, 256, 0, stream>>>(ei, flags, rbBuf, e, nbins);
    k_colscan<<<nbins, 1024, 0, stream>>>(rbBuf, binCnt, nblk, nbins);
    k_scanbins<<<1, 1024, 0, stream>>>(binCnt, binStart, nbins, e);
    k_binplace<<<nblk, 256, 0, stream>>>(ei, flags, binStart, rbBuf, col, e, nbins);
    k_place<<<nbins, 256, 0, stream>>>(col, binStart, rowStart, n, e);

    // initial embedding (bf16 h table)
    k_argmax_embed<<<ngrid4, 256, 0, stream>>>(x, emb, flags, hcur, n);

    // 3 thread-per-node gather+combine layers (no DS-pipe hot path)
    k_gc <<<ngrid256, 256, 0, stream>>>(col, rowStart, hcur,  W1l, b1, W1r, flags, hnext, n, e);
    k_gc <<<ngrid256, 256, 0, stream>>>(col, rowStart, hnext, W2l, b2, W2r, flags, hcur,  n, e);
    k_gc3<<<ngrid256, 256, 0, stream>>>(col, rowStart, hcur,  W3l, b3, W3r, flags, h3,    n, e);

    // pool + softmax
    k_pool_softmax<<<NGRAPH, 64, 0, stream>>>(h3, bat, flags, d_out, n);
}

// Round 11
// 613.171 us; speedup vs baseline: 3.9042x; 1.2640x over previous
//
#include <hip/hip_runtime.h>
#include <hip/hip_bf16.h>

#define N_FEAT 128
#define HID 16
#define NCLS 10
#define NGRAPH 1024
#define SHIFT 7            // 128 nodes per coarse bin
#define NBMAX 1024         // supports n <= 131072
#define CAP 24576          // LDS staging entries in k_place (96 KB)
#define CH 8192            // edges per binning block
#define EPB (CH / 256)     // edges per thread in binning kernels

__device__ __forceinline__ float u2f(unsigned int u) {
    union { unsigned int u; float f; } c; c.u = u; return c.f;
}
__device__ __forceinline__ float bf2f(__hip_bfloat16 b) {
    return __bfloat162float(b);
}
__device__ __forceinline__ unsigned short f2us(float f) {
    union { __hip_bfloat16 b; unsigned short u; } c;
    c.b = __float2bfloat16(f);
    return c.u;
}
__device__ __forceinline__ float ldw(const void* __restrict__ p, int i, int isbf) {
    return isbf ? bf2f(((const __hip_bfloat16*)p)[i]) : ((const float*)p)[i];
}
// unpack 8 bf16 packed in a uint4 into f[0..7]
__device__ __forceinline__ void unp8(uint4 v, float* f) {
    f[0] = u2f(v.x << 16); f[1] = u2f(v.x & 0xffff0000u);
    f[2] = u2f(v.y << 16); f[3] = u2f(v.y & 0xffff0000u);
    f[4] = u2f(v.z << 16); f[5] = u2f(v.z & 0xffff0000u);
    f[6] = u2f(v.w << 16); f[7] = u2f(v.w & 0xffff0000u);
}

// ---------------------------------------------------------------------------
// K0: runtime dtype probes (kept — these made R3 pass).
__global__ void k_detect(const int* __restrict__ ei,
                         const unsigned int* __restrict__ xw,
                         int* __restrict__ flags) {
    if (blockIdx.x == 0 && threadIdx.x == 0) {
        int nz = 0;
        for (int i = 1; i < 256; i += 2) nz |= ei[i];
        flags[0] = (nz == 0) ? 1 : 0;
        int cnt = 0;
        for (int i = 0; i < 64; i++) {
            unsigned int ef = xw[i] & 0x7F80u;
            if (ef >= 0x3C00u && ef <= 0x4080u) cnt++;
        }
        flags[1] = (cnt >= 32) ? 1 : 0;
    }
}

// ---------------------------------------------------------------------------
// K1: h0[i] = emb[argmax(x[i,:])] — one 64-lane wave per node; bf16 output.
__global__ void k_argmax_embed(const void* __restrict__ x,
                               const void* __restrict__ emb,
                               const int* __restrict__ flags,
                               unsigned short* __restrict__ h, int n) {
    int wave = (int)((blockIdx.x * (unsigned)blockDim.x + threadIdx.x) >> 6);
    int lane = threadIdx.x & 63;
    if (wave >= n) return;
    int isbf = flags[1];
    float v0, v1;
    if (isbf) {
        const unsigned int* row =
            (const unsigned int*)((const __hip_bfloat16*)x + (size_t)wave * N_FEAT);
        unsigned int u = row[lane];
        v0 = u2f(u << 16);
        v1 = u2f(u & 0xffff0000u);
    } else {
        const float2* row = (const float2*)((const float*)x + (size_t)wave * N_FEAT);
        float2 u = row[lane];
        v0 = u.x; v1 = u.y;
    }
    float bv; int bi;
    if (v1 > v0) { bv = v1; bi = 2 * lane + 1; }
    else         { bv = v0; bi = 2 * lane; }
    #pragma unroll
    for (int off = 1; off < 64; off <<= 1) {
        float ov = __shfl_xor(bv, off);
        int   oi = __shfl_xor(bi, off);
        if (ov > bv || (ov == bv && oi < bi)) { bv = ov; bi = oi; }
    }
    if (lane < HID) {
        unsigned short us;
        if (isbf) us = ((const unsigned short*)emb)[bi * HID + lane];  // exact copy
        else      us = f2us(((const float*)emb)[bi * HID + lane]);
        h[(size_t)wave * HID + lane] = us;
    }
}

// ---------------------------------------------------------------------------
// K2a: per-block LDS bin histogram -> plain coalesced store of the count row.
__global__ void k_binhist(const int* __restrict__ ei, const int* __restrict__ flags,
                          int* __restrict__ rbBuf, int e, int nbins) {
    __shared__ int lh[NBMAX];
    int t = threadIdx.x;
    for (int b = t; b < nbins; b += 256) lh[b] = 0;
    __syncthreads();
    int base = blockIdx.x * CH;
    int sh = flags[0];
    for (int j = 0; j < EPB; j++) {
        int i = base + j * 256 + t;
        if (i < e) {
            int d = ei[((size_t)(e + i)) << sh];
            atomicAdd(&lh[d >> SHIFT], 1);
        }
    }
    __syncthreads();
    int* row = rbBuf + (size_t)blockIdx.x * nbins;
    for (int b = t; b < nbins; b += 256) row[b] = lh[b];
}

// K2b: per-bin exclusive scan over blocks (in place).
__global__ void k_colscan(int* __restrict__ rbBuf, int* __restrict__ binCnt,
                          int nblk, int nbins) {
    __shared__ int ls[1024];
    int b = blockIdx.x, t = threadIdx.x;
    int v = (t < nblk) ? rbBuf[(size_t)t * nbins + b] : 0;
    ls[t] = v;
    __syncthreads();
    #pragma unroll
    for (int off = 1; off < 1024; off <<= 1) {
        int w = (t >= off) ? ls[t - off] : 0;
        __syncthreads();
        ls[t] += w;
        __syncthreads();
    }
    if (t < nblk) rbBuf[(size_t)t * nbins + b] = ls[t] - v;
    if (t == 1023) binCnt[b] = ls[t];
}

// K2c: exclusive scan of binCnt -> binStart.
__global__ void k_scanbins(const int* __restrict__ binCnt,
                           int* __restrict__ binStart, int nbins, int e) {
    __shared__ int ls[1024];
    int t = threadIdx.x;
    int v = (t < nbins) ? binCnt[t] : 0;
    ls[t] = v;
    __syncthreads();
    #pragma unroll
    for (int off = 1; off < 1024; off <<= 1) {
        int w = (t >= off) ? ls[t - off] : 0;
        __syncthreads();
        ls[t] += w;
        __syncthreads();
    }
    if (t < nbins) binStart[t] = ls[t] - v;
    if (t == 0) binStart[nbins] = e;
}

// K2d: coarse placement, LDS-sorted for coalesced writes (R7 win — kept).
__global__ __launch_bounds__(256) void k_binplace(
        const int* __restrict__ ei, const int* __restrict__ flags,
        const int* __restrict__ binStart, const int* __restrict__ rbBuf,
        int* __restrict__ col, int e, int nbins) {
    __shared__ int cnt[NBMAX];
    __shared__ int ldsOff[NBMAX];
    __shared__ int ldsBase[NBMAX];
    __shared__ int ps[256];
    __shared__ int stage[CH];
    __shared__ unsigned short binOf[CH];
    int t = threadIdx.x;
    for (int b = t; b < nbins; b += 256) cnt[b] = 0;
    __syncthreads();
    int base = blockIdx.x * CH;
    int sh = flags[0];
    int myV[EPB]; short myB[EPB];
    for (int j = 0; j < EPB; j++) {
        int i = base + j * 256 + t;
        if (i < e) {
            int s = ei[((size_t)i) << sh];
            int d = ei[((size_t)(e + i)) << sh];
            myV[j] = (s << SHIFT) | (d & ((1 << SHIFT) - 1));
            int b2 = d >> SHIFT;
            myB[j] = (short)b2;
            atomicAdd(&cnt[b2], 1);
        } else myB[j] = -1;
    }
    __syncthreads();
    int c[4]; int lsum = 0;
    int bb = t * 4;
    #pragma unroll
    for (int k = 0; k < 4; k++) {
        int b2 = bb + k;
        c[k] = (b2 < nbins) ? cnt[b2] : 0;
        lsum += c[k];
    }
    ps[t] = lsum;
    __syncthreads();
    #pragma unroll
    for (int off = 1; off < 256; off <<= 1) {
        int w = (t >= off) ? ps[t - off] : 0;
        __syncthreads();
        ps[t] += w;
        __syncthreads();
    }
    int run = ps[t] - lsum;
    #pragma unroll
    for (int k = 0; k < 4; k++) {
        int b2 = bb + k;
        if (b2 < nbins) ldsOff[b2] = run;
        run += c[k];
    }
    __syncthreads();
    const int* rb = rbBuf + (size_t)blockIdx.x * nbins;
    for (int b2 = t; b2 < nbins; b2 += 256) {
        ldsBase[b2] = binStart[b2] + rb[b2] - ldsOff[b2];
        cnt[b2] = 0;
    }
    __syncthreads();
    for (int j = 0; j < EPB; j++) {
        if (myB[j] >= 0) {
            int b2 = myB[j];
            int r = atomicAdd(&cnt[b2], 1);
            int p = ldsOff[b2] + r;
            stage[p] = myV[j];
            binOf[p] = (unsigned short)b2;
        }
    }
    __syncthreads();
    int total = e - base;
    if (total > CH) total = CH;
    for (int i = t; i < total; i += 256) {
        int b2 = binOf[i];
        col[ldsBase[b2] + i] = stage[i];
    }
}

// K2e: fine placement + per-node rowStart.
__global__ void k_place(int* __restrict__ col, const int* __restrict__ binStart,
                        int* __restrict__ rowStart, int n, int e) {
    __shared__ int stage[CAP];
    __shared__ int cntN[1 << SHIFT];
    __shared__ int sc[1 << SHIFT];
    __shared__ int rs[1 << SHIFT];
    int b = blockIdx.x;
    int t = threadIdx.x;
    int nb = b << SHIFT;
    int s0 = binStart[b];
    int s1 = binStart[b + 1];
    int cnt = s1 - s0;
    if (t < (1 << SHIFT)) cntN[t] = 0;
    bool st = (cnt <= CAP);
    __syncthreads();
    for (int i = t; i < cnt; i += 256) {
        int v = col[s0 + i];
        if (st) stage[i] = v;
        atomicAdd(&cntN[v & ((1 << SHIFT) - 1)], 1);
    }
    __syncthreads();
    if (t < (1 << SHIFT)) sc[t] = cntN[t];
    __syncthreads();
    #pragma unroll
    for (int off = 1; off < (1 << SHIFT); off <<= 1) {
        int w = 0;
        if (t < (1 << SHIFT) && t >= off) w = sc[t - off];
        __syncthreads();
        if (t < (1 << SHIFT)) sc[t] += w;
        __syncthreads();
    }
    if (t < (1 << SHIFT)) {
        int start = s0 + sc[t] - cntN[t];
        rs[t] = start;
        int node = nb + t;
        if (node < n) rowStart[node] = start;
        cntN[t] = 0;
    }
    __syncthreads();
    for (int i = t; i < cnt; i += 256) {
        int v = st ? stage[i] : col[s0 + i];
        int dl = v & ((1 << SHIFT) - 1);
        int r = atomicAdd(&cntN[dl], 1);
        col[rs[dl] + r] = v >> SHIFT;
    }
}

// ---------------------------------------------------------------------------
// K3: 2-threads-per-node fused gather + combine, layers 1/2 (k-split).
// Thread j of a node accumulates features [8j,8j+8) over ALL edges (one
// uint4/edge, pair shares col broadcast + row line). No reduction needed for
// the mean. Tiny conflict-free LDS exchange assembles a[16]; full in-thread
// matmul with wave-uniform weight reads; split 16B stores. Cached col (no nt).
__global__ __launch_bounds__(256) void k_gc(
        const int* __restrict__ col, const int* __restrict__ rowStart,
        const unsigned short* __restrict__ hin,
        const void* __restrict__ Wl, const void* __restrict__ bia,
        const void* __restrict__ Wr, const int* __restrict__ flags,
        unsigned short* __restrict__ hout, int n, int e) {
    __shared__ float wl[HID][HID], wr[HID][HID], bb[HID];
    __shared__ float fbuf[HID][128];      // [feature][node-local]
    int t = threadIdx.x;
    int isbf = flags[1];
    if (t < HID * HID) {
        wl[t >> 4][t & 15] = ldw(Wl, t, isbf);
        wr[t >> 4][t & 15] = ldw(Wr, t, isbf);
    }
    if (t < HID) bb[t] = ldw(bia, t, isbf);
    __syncthreads();
    int nl = t >> 1;                      // node-local 0..127
    int j  = t & 1;                       // feature-half
    int node = blockIdx.x * 128 + nl;
    if (node >= n) return;
    int lo = rowStart[node];
    int hi = (node + 1 < n) ? rowStart[node + 1] : e;
    const uint4* h4 = (const uint4*)hin;
    float a8[8];
    #pragma unroll
    for (int k = 0; k < 8; k++) a8[k] = 0.0f;
    for (int i = lo; i < hi; i++) {
        int s = col[i];                   // cached: pair-broadcast + seq reuse
        uint4 v = h4[(size_t)s * 2 + j];
        float f[8];
        unp8(v, f);
        #pragma unroll
        for (int k = 0; k < 8; k++) a8[k] += f[k];
    }
    float invd = 1.0f / fmaxf((float)(hi - lo), 1.0f);
    #pragma unroll
    for (int k = 0; k < 8; k++) a8[k] *= invd;
    // exchange: feature-major, conflict-free (2 lanes/bank = free)
    #pragma unroll
    for (int k = 0; k < 8; k++) fbuf[8 * j + k][nl] = a8[k];
    float a[HID];
    #pragma unroll
    for (int k = 0; k < HID; k++) a[k] = fbuf[k][nl];   // intra-wave, in-order DS
    float hb[HID];
    unp8(h4[(size_t)node * 2], hb);
    unp8(h4[(size_t)node * 2 + 1], hb + 8);
    float o[HID]; float sq = 0.0f;
    #pragma unroll
    for (int f = 0; f < HID; f++) {
        float acc = bb[f];
        #pragma unroll
        for (int k = 0; k < HID; k++)
            acc += a[k] * wl[f][k] + hb[k] * wr[f][k];
        o[f] = acc;
        sq += acc * acc;
    }
    float inn = 1.0f / fmaxf(sqrtf(sq), 1e-12f);
    uint4 w;
    unsigned int* wp = (unsigned int*)&w;
    #pragma unroll
    for (int q = 0; q < 4; q++) {
        unsigned int l0 = f2us(fmaxf(o[8 * j + 2 * q] * inn, 0.0f));
        unsigned int h0 = f2us(fmaxf(o[8 * j + 2 * q + 1] * inn, 0.0f));
        wp[q] = l0 | (h0 << 16);
    }
    ((uint4*)hout)[(size_t)node * 2 + j] = w;
}

// K4: 2-threads-per-node layer 3 (10 outputs, no ReLU, fp32 h3).
__global__ __launch_bounds__(256) void k_gc3(
        const int* __restrict__ col, const int* __restrict__ rowStart,
        const unsigned short* __restrict__ hin,
        const void* __restrict__ Wl, const void* __restrict__ bia,
        const void* __restrict__ Wr, const int* __restrict__ flags,
        float* __restrict__ h3, int n, int e) {
    __shared__ float wl[NCLS][HID], wr[NCLS][HID], bb[NCLS];
    __shared__ float fbuf[HID][128];
    int t = threadIdx.x;
    int isbf = flags[1];
    if (t < NCLS * HID) {
        wl[t >> 4][t & 15] = ldw(Wl, t, isbf);
        wr[t >> 4][t & 15] = ldw(Wr, t, isbf);
    }
    if (t < NCLS) bb[t] = ldw(bia, t, isbf);
    __syncthreads();
    int nl = t >> 1;
    int j  = t & 1;
    int node = blockIdx.x * 128 + nl;
    if (node >= n) return;
    int lo = rowStart[node];
    int hi = (node + 1 < n) ? rowStart[node + 1] : e;
    const uint4* h4 = (const uint4*)hin;
    float a8[8];
    #pragma unroll
    for (int k = 0; k < 8; k++) a8[k] = 0.0f;
    for (int i = lo; i < hi; i++) {
        int s = col[i];
        uint4 v = h4[(size_t)s * 2 + j];
        float f[8];
        unp8(v, f);
        #pragma unroll
        for (int k = 0; k < 8; k++) a8[k] += f[k];
    }
    float invd = 1.0f / fmaxf((float)(hi - lo), 1.0f);
    #pragma unroll
    for (int k = 0; k < 8; k++) a8[k] *= invd;
    #pragma unroll
    for (int k = 0; k < 8; k++) fbuf[8 * j + k][nl] = a8[k];
    float a[HID];
    #pragma unroll
    for (int k = 0; k < HID; k++) a[k] = fbuf[k][nl];
    float hb[HID];
    unp8(h4[(size_t)node * 2], hb);
    unp8(h4[(size_t)node * 2 + 1], hb + 8);
    float o[NCLS]; float sq = 0.0f;
    #pragma unroll
    for (int f = 0; f < NCLS; f++) {
        float acc = bb[f];
        #pragma unroll
        for (int k = 0; k < HID; k++)
            acc += a[k] * wl[f][k] + hb[k] * wr[f][k];
        o[f] = acc;
        sq += acc * acc;
    }
    float inn = 1.0f / fmaxf(sqrtf(sq), 1e-12f);
    float* op = h3 + (size_t)node * NCLS;
    if (j == 0) {
        #pragma unroll
        for (int f = 0; f < 8; f++) op[f] = o[f] * inn;
    } else {
        op[8] = o[8] * inn;
        op[9] = o[9] * inn;
    }
}

// ---------------------------------------------------------------------------
// K5: per-graph mean pool (batch sorted -> binary search) + softmax.
__device__ __forceinline__ int lbound(const int* __restrict__ a, int n, int key, int sh) {
    int lo = 0, hi = n;
    while (lo < hi) {
        int mid = (lo + hi) >> 1;
        if (a[((size_t)mid) << sh] < key) lo = mid + 1; else hi = mid;
    }
    return lo;
}

__global__ void k_pool_softmax(const float* __restrict__ h3,
                               const int* __restrict__ batch,
                               const int* __restrict__ flags,
                               void* __restrict__ out, int n) {
    int g = blockIdx.x;
    int lane = threadIdx.x;
    int sh = flags[0];
    int lo = lbound(batch, n, g, sh);
    int hi = lbound(batch, n, g + 1, sh);
    float acc[NCLS];
    #pragma unroll
    for (int c = 0; c < NCLS; c++) acc[c] = 0.0f;
    for (int i = lo + lane; i < hi; i += 64) {
        const float* r = h3 + (size_t)i * NCLS;
        #pragma unroll
        for (int c = 0; c < NCLS; c++) acc[c] += r[c];
    }
    #pragma unroll
    for (int c = 0; c < NCLS; c++) {
        #pragma unroll
        for (int off = 1; off < 64; off <<= 1)
            acc[c] += __shfl_xor(acc[c], off);
    }
    float invc = 1.0f / fmaxf((float)(hi - lo), 1.0f);
    float m = -1e30f;
    #pragma unroll
    for (int c = 0; c < NCLS; c++) { acc[c] *= invc; m = fmaxf(m, acc[c]); }
    float s = 0.0f;
    #pragma unroll
    for (int c = 0; c < NCLS; c++) { acc[c] = expf(acc[c] - m); s += acc[c]; }
    float invs = 1.0f / s;
    if (lane < NCLS) {
        float v = acc[lane] * invs;
        size_t idx = (size_t)g * NCLS + lane;
        if (flags[1]) ((__hip_bfloat16*)out)[idx] = __float2bfloat16(v);
        else          ((float*)out)[idx] = v;
    }
}

// ---------------------------------------------------------------------------
extern "C" void kernel_launch(void* const* d_in, const int* in_sizes, int n_in,
                              void* d_out, int out_size, void* d_ws, size_t ws_size,
                              hipStream_t stream) {
    const void* x   = d_in[0];
    const int*  ei  = (const int*)d_in[1];
    const int*  bat = (const int*)d_in[2];
    const void* emb = d_in[3];
    const void* W1l = d_in[4];  const void* b1 = d_in[5];  const void* W1r = d_in[6];
    const void* W2l = d_in[7];  const void* b2 = d_in[8];  const void* W2r = d_in[9];
    const void* W3l = d_in[10]; const void* b3 = d_in[11]; const void* W3r = d_in[12];

    int n = in_sizes[0] / N_FEAT;
    int e = in_sizes[1] / 2;
    int nbins = (n + (1 << SHIFT) - 1) >> SHIFT;
    int nblk  = (e + CH - 1) / CH;

    // ws: hcur[16n] bf16 | hnext[16n] bf16 | h3[10n] f32 | col[e] |
    //     rowStart[n] | binCnt | binStart | rbBuf[nblk*nbins] | flags
    unsigned short* hcur  = (unsigned short*)d_ws;
    unsigned short* hnext = hcur + (size_t)n * HID;
    float* h3       = (float*)(hnext + (size_t)n * HID);
    int*   col      = (int*)(h3 + (size_t)n * NCLS);
    int*   rowStart = col + e;
    int*   binCnt   = rowStart + n;
    int*   binStart = binCnt + nbins;
    int*   rbBuf    = binStart + (nbins + 1);
    int*   flags    = rbBuf + (size_t)nblk * nbins;

    int ngrid4   = (n + 3) / 4;
    int ngrid128 = (n + 127) / 128;       // 2 threads/node, 256-thread blocks

    // probes + CSR build
    k_detect<<<1, 64, 0, stream>>>(ei, (const unsigned int*)x, flags);
    k_binhist<<<nblk, 256, 0, stream>>>(ei, flags, rbBuf, e, nbins);
    k_colscan<<<nbins, 1024, 0, stream>>>(rbBuf, binCnt, nblk, nbins);
    k_scanbins<<<1, 1024, 0, stream>>>(binCnt, binStart, nbins, e);
    k_binplace<<<nblk, 256, 0, stream>>>(ei, flags, binStart, rbBuf, col, e, nbins);
    k_place<<<nbins, 256, 0, stream>>>(col, binStart, rowStart, n, e);

    // initial embedding (bf16 h table)
    k_argmax_embed<<<ngrid4, 256, 0, stream>>>(x, emb, flags, hcur, n);

    // 3 gather+combine layers (2 threads/node, k-split, cached col)
    k_gc <<<ngrid128, 256, 0, stream>>>(col, rowStart, hcur,  W1l, b1, W1r, flags, hnext, n, e);
    k_gc <<<ngrid128, 256, 0, stream>>>(col, rowStart, hnext, W2l, b2, W2r, flags, hcur,  n, e);
    k_gc3<<<ngrid128, 256, 0, stream>>>(col, rowStart, hcur,  W3l, b3, W3r, flags, h3,    n, e);

    // pool + softmax
    k_pool_softmax<<<NGRAPH, 64, 0, stream>>>(h3, bat, flags, d_out, n);
}

// Round 12
// 565.260 us; speedup vs baseline: 4.2351x; 1.0848x over previous
//
#include <hip/hip_runtime.h>
#include <hip/hip_bf16.h>

#define N_FEAT 128
#define HID 16
#define NCLS 10
#define NGRAPH 1024
#define SHIFT 7            // 128 nodes per coarse bin
#define NBMAX 1024         // supports n <= 131072
#define CAP 24576          // LDS staging entries in k_place (96 KB)
#define GCAP 10240         // LDS staging entries in k_gc (40 KB, ~22 sigma)
#define CH 8192            // edges per binning block
#define EPB (CH / 256)     // edges per thread in binning kernels

__device__ __forceinline__ float u2f(unsigned int u) {
    union { unsigned int u; float f; } c; c.u = u; return c.f;
}
__device__ __forceinline__ float bf2f(__hip_bfloat16 b) {
    return __bfloat162float(b);
}
__device__ __forceinline__ unsigned short f2us(float f) {
    union { __hip_bfloat16 b; unsigned short u; } c;
    c.b = __float2bfloat16(f);
    return c.u;
}
__device__ __forceinline__ float ldw(const void* __restrict__ p, int i, int isbf) {
    return isbf ? bf2f(((const __hip_bfloat16*)p)[i]) : ((const float*)p)[i];
}
// unpack 8 bf16 packed in a uint4 into f[0..7]
__device__ __forceinline__ void unp8(uint4 v, float* f) {
    f[0] = u2f(v.x << 16); f[1] = u2f(v.x & 0xffff0000u);
    f[2] = u2f(v.y << 16); f[3] = u2f(v.y & 0xffff0000u);
    f[4] = u2f(v.z << 16); f[5] = u2f(v.z & 0xffff0000u);
    f[6] = u2f(v.w << 16); f[7] = u2f(v.w & 0xffff0000u);
}

// ---------------------------------------------------------------------------
// K0: runtime dtype probes (kept — these made R3 pass).
__global__ void k_detect(const int* __restrict__ ei,
                         const unsigned int* __restrict__ xw,
                         int* __restrict__ flags) {
    if (blockIdx.x == 0 && threadIdx.x == 0) {
        int nz = 0;
        for (int i = 1; i < 256; i += 2) nz |= ei[i];
        flags[0] = (nz == 0) ? 1 : 0;
        int cnt = 0;
        for (int i = 0; i < 64; i++) {
            unsigned int ef = xw[i] & 0x7F80u;
            if (ef >= 0x3C00u && ef <= 0x4080u) cnt++;
        }
        flags[1] = (cnt >= 32) ? 1 : 0;
    }
}

// ---------------------------------------------------------------------------
// K1: h0[i] = emb[argmax(x[i,:])] — one 64-lane wave per node; bf16 output.
__global__ void k_argmax_embed(const void* __restrict__ x,
                               const void* __restrict__ emb,
                               const int* __restrict__ flags,
                               unsigned short* __restrict__ h, int n) {
    int wave = (int)((blockIdx.x * (unsigned)blockDim.x + threadIdx.x) >> 6);
    int lane = threadIdx.x & 63;
    if (wave >= n) return;
    int isbf = flags[1];
    float v0, v1;
    if (isbf) {
        const unsigned int* row =
            (const unsigned int*)((const __hip_bfloat16*)x + (size_t)wave * N_FEAT);
        unsigned int u = row[lane];
        v0 = u2f(u << 16);
        v1 = u2f(u & 0xffff0000u);
    } else {
        const float2* row = (const float2*)((const float*)x + (size_t)wave * N_FEAT);
        float2 u = row[lane];
        v0 = u.x; v1 = u.y;
    }
    float bv; int bi;
    if (v1 > v0) { bv = v1; bi = 2 * lane + 1; }
    else         { bv = v0; bi = 2 * lane; }
    #pragma unroll
    for (int off = 1; off < 64; off <<= 1) {
        float ov = __shfl_xor(bv, off);
        int   oi = __shfl_xor(bi, off);
        if (ov > bv || (ov == bv && oi < bi)) { bv = ov; bi = oi; }
    }
    if (lane < HID) {
        unsigned short us;
        if (isbf) us = ((const unsigned short*)emb)[bi * HID + lane];  // exact copy
        else      us = f2us(((const float*)emb)[bi * HID + lane]);
        h[(size_t)wave * HID + lane] = us;
    }
}

// ---------------------------------------------------------------------------
// K2a: per-block LDS bin histogram -> plain coalesced store of the count row.
__global__ void k_binhist(const int* __restrict__ ei, const int* __restrict__ flags,
                          int* __restrict__ rbBuf, int e, int nbins) {
    __shared__ int lh[NBMAX];
    int t = threadIdx.x;
    for (int b = t; b < nbins; b += 256) lh[b] = 0;
    __syncthreads();
    int base = blockIdx.x * CH;
    int sh = flags[0];
    for (int j = 0; j < EPB; j++) {
        int i = base + j * 256 + t;
        if (i < e) {
            int d = ei[((size_t)(e + i)) << sh];
            atomicAdd(&lh[d >> SHIFT], 1);
        }
    }
    __syncthreads();
    int* row = rbBuf + (size_t)blockIdx.x * nbins;
    for (int b = t; b < nbins; b += 256) row[b] = lh[b];
}

// K2b: per-bin exclusive scan over blocks (in place).
__global__ void k_colscan(int* __restrict__ rbBuf, int* __restrict__ binCnt,
                          int nblk, int nbins) {
    __shared__ int ls[1024];
    int b = blockIdx.x, t = threadIdx.x;
    int v = (t < nblk) ? rbBuf[(size_t)t * nbins + b] : 0;
    ls[t] = v;
    __syncthreads();
    #pragma unroll
    for (int off = 1; off < 1024; off <<= 1) {
        int w = (t >= off) ? ls[t - off] : 0;
        __syncthreads();
        ls[t] += w;
        __syncthreads();
    }
    if (t < nblk) rbBuf[(size_t)t * nbins + b] = ls[t] - v;
    if (t == 1023) binCnt[b] = ls[t];
}

// K2c: exclusive scan of binCnt -> binStart.
__global__ void k_scanbins(const int* __restrict__ binCnt,
                           int* __restrict__ binStart, int nbins, int e) {
    __shared__ int ls[1024];
    int t = threadIdx.x;
    int v = (t < nbins) ? binCnt[t] : 0;
    ls[t] = v;
    __syncthreads();
    #pragma unroll
    for (int off = 1; off < 1024; off <<= 1) {
        int w = (t >= off) ? ls[t - off] : 0;
        __syncthreads();
        ls[t] += w;
        __syncthreads();
    }
    if (t < nbins) binStart[t] = ls[t] - v;
    if (t == 0) binStart[nbins] = e;
}

// K2d: coarse placement, LDS-sorted for coalesced writes (R7 win — kept).
__global__ __launch_bounds__(256) void k_binplace(
        const int* __restrict__ ei, const int* __restrict__ flags,
        const int* __restrict__ binStart, const int* __restrict__ rbBuf,
        int* __restrict__ col, int e, int nbins) {
    __shared__ int cnt[NBMAX];
    __shared__ int ldsOff[NBMAX];
    __shared__ int ldsBase[NBMAX];
    __shared__ int ps[256];
    __shared__ int stage[CH];
    __shared__ unsigned short binOf[CH];
    int t = threadIdx.x;
    for (int b = t; b < nbins; b += 256) cnt[b] = 0;
    __syncthreads();
    int base = blockIdx.x * CH;
    int sh = flags[0];
    int myV[EPB]; short myB[EPB];
    for (int j = 0; j < EPB; j++) {
        int i = base + j * 256 + t;
        if (i < e) {
            int s = ei[((size_t)i) << sh];
            int d = ei[((size_t)(e + i)) << sh];
            myV[j] = (s << SHIFT) | (d & ((1 << SHIFT) - 1));
            int b2 = d >> SHIFT;
            myB[j] = (short)b2;
            atomicAdd(&cnt[b2], 1);
        } else myB[j] = -1;
    }
    __syncthreads();
    int c[4]; int lsum = 0;
    int bb = t * 4;
    #pragma unroll
    for (int k = 0; k < 4; k++) {
        int b2 = bb + k;
        c[k] = (b2 < nbins) ? cnt[b2] : 0;
        lsum += c[k];
    }
    ps[t] = lsum;
    __syncthreads();
    #pragma unroll
    for (int off = 1; off < 256; off <<= 1) {
        int w = (t >= off) ? ps[t - off] : 0;
        __syncthreads();
        ps[t] += w;
        __syncthreads();
    }
    int run = ps[t] - lsum;
    #pragma unroll
    for (int k = 0; k < 4; k++) {
        int b2 = bb + k;
        if (b2 < nbins) ldsOff[b2] = run;
        run += c[k];
    }
    __syncthreads();
    const int* rb = rbBuf + (size_t)blockIdx.x * nbins;
    for (int b2 = t; b2 < nbins; b2 += 256) {
        ldsBase[b2] = binStart[b2] + rb[b2] - ldsOff[b2];
        cnt[b2] = 0;
    }
    __syncthreads();
    for (int j = 0; j < EPB; j++) {
        if (myB[j] >= 0) {
            int b2 = myB[j];
            int r = atomicAdd(&cnt[b2], 1);
            int p = ldsOff[b2] + r;
            stage[p] = myV[j];
            binOf[p] = (unsigned short)b2;
        }
    }
    __syncthreads();
    int total = e - base;
    if (total > CH) total = CH;
    for (int i = t; i < total; i += 256) {
        int b2 = binOf[i];
        col[ldsBase[b2] + i] = stage[i];
    }
}

// K2e: fine placement + per-node rowStart.
__global__ void k_place(int* __restrict__ col, const int* __restrict__ binStart,
                        int* __restrict__ rowStart, int n, int e) {
    __shared__ int stage[CAP];
    __shared__ int cntN[1 << SHIFT];
    __shared__ int sc[1 << SHIFT];
    __shared__ int rs[1 << SHIFT];
    int b = blockIdx.x;
    int t = threadIdx.x;
    int nb = b << SHIFT;
    int s0 = binStart[b];
    int s1 = binStart[b + 1];
    int cnt = s1 - s0;
    if (t < (1 << SHIFT)) cntN[t] = 0;
    bool st = (cnt <= CAP);
    __syncthreads();
    for (int i = t; i < cnt; i += 256) {
        int v = col[s0 + i];
        if (st) stage[i] = v;
        atomicAdd(&cntN[v & ((1 << SHIFT) - 1)], 1);
    }
    __syncthreads();
    if (t < (1 << SHIFT)) sc[t] = cntN[t];
    __syncthreads();
    #pragma unroll
    for (int off = 1; off < (1 << SHIFT); off <<= 1) {
        int w = 0;
        if (t < (1 << SHIFT) && t >= off) w = sc[t - off];
        __syncthreads();
        if (t < (1 << SHIFT)) sc[t] += w;
        __syncthreads();
    }
    if (t < (1 << SHIFT)) {
        int start = s0 + sc[t] - cntN[t];
        rs[t] = start;
        int node = nb + t;
        if (node < n) rowStart[node] = start;
        cntN[t] = 0;
    }
    __syncthreads();
    for (int i = t; i < cnt; i += 256) {
        int v = st ? stage[i] : col[s0 + i];
        int dl = v & ((1 << SHIFT) - 1);
        int r = atomicAdd(&cntN[dl], 1);
        col[rs[dl] + r] = v >> SHIFT;
    }
}

// ---------------------------------------------------------------------------
// K3: 2-threads-per-node gather+combine, layers 1/2 — bin-aligned blocks with
// LDS-staged col. Staging load is coalesced + nt (line fully consumed at
// once, so col never pollutes L2 -> bf16 table stays L2-resident; this is
// the R11 FETCH=119MB fix). Pairs then consume edge ids from LDS.
__global__ __launch_bounds__(256) void k_gc(
        const int* __restrict__ col, const int* __restrict__ rowStart,
        const int* __restrict__ binStart,
        const unsigned short* __restrict__ hin,
        const void* __restrict__ Wl, const void* __restrict__ bia,
        const void* __restrict__ Wr, const int* __restrict__ flags,
        unsigned short* __restrict__ hout, int n, int e) {
    __shared__ int ecol[GCAP];
    __shared__ float wl[HID][HID], wr[HID][HID], bb[HID];
    __shared__ float fbuf[HID][128];      // [feature][node-local]
    int t = threadIdx.x;
    int b = blockIdx.x;
    int isbf = flags[1];
    if (t < HID * HID) {
        wl[t >> 4][t & 15] = ldw(Wl, t, isbf);
        wr[t >> 4][t & 15] = ldw(Wr, t, isbf);
    }
    if (t < HID) bb[t] = ldw(bia, t, isbf);
    int s0 = binStart[b];
    int s1 = binStart[b + 1];
    int cnt = s1 - s0;
    int scnt = (cnt < GCAP) ? cnt : GCAP;
    for (int i = t; i < scnt; i += 256)
        ecol[i] = __builtin_nontemporal_load(col + s0 + i);
    __syncthreads();
    int nl = t >> 1;                      // node-local 0..127
    int j  = t & 1;                       // feature-half
    int node = (b << SHIFT) + nl;
    if (node >= n) return;
    int lo = rowStart[node];
    int hi = (node + 1 < n) ? rowStart[node + 1] : e;
    const uint4* h4 = (const uint4*)hin;
    float a8[8];
    #pragma unroll
    for (int k = 0; k < 8; k++) a8[k] = 0.0f;
    for (int i = lo; i < hi; i++) {
        int idx = i - s0;
        int s = (idx < GCAP) ? ecol[idx] : col[i];
        uint4 v = h4[(size_t)s * 2 + j];
        float f[8];
        unp8(v, f);
        #pragma unroll
        for (int k = 0; k < 8; k++) a8[k] += f[k];
    }
    float invd = 1.0f / fmaxf((float)(hi - lo), 1.0f);
    #pragma unroll
    for (int k = 0; k < 8; k++) a8[k] *= invd;
    #pragma unroll
    for (int k = 0; k < 8; k++) fbuf[8 * j + k][nl] = a8[k];
    float a[HID];
    #pragma unroll
    for (int k = 0; k < HID; k++) a[k] = fbuf[k][nl];   // intra-wave pair, in-order DS
    float hb[HID];
    unp8(h4[(size_t)node * 2], hb);
    unp8(h4[(size_t)node * 2 + 1], hb + 8);
    float o[HID]; float sq = 0.0f;
    #pragma unroll
    for (int f = 0; f < HID; f++) {
        float acc = bb[f];
        #pragma unroll
        for (int k = 0; k < HID; k++)
            acc += a[k] * wl[f][k] + hb[k] * wr[f][k];
        o[f] = acc;
        sq += acc * acc;
    }
    float inn = 1.0f / fmaxf(sqrtf(sq), 1e-12f);
    uint4 w;
    unsigned int* wp = (unsigned int*)&w;
    #pragma unroll
    for (int q = 0; q < 4; q++) {
        unsigned int l0 = f2us(fmaxf(o[8 * j + 2 * q] * inn, 0.0f));
        unsigned int h0 = f2us(fmaxf(o[8 * j + 2 * q + 1] * inn, 0.0f));
        wp[q] = l0 | (h0 << 16);
    }
    ((uint4*)hout)[(size_t)node * 2 + j] = w;
}

// K4: same structure, layer 3 (10 outputs, no ReLU, fp32 h3).
__global__ __launch_bounds__(256) void k_gc3(
        const int* __restrict__ col, const int* __restrict__ rowStart,
        const int* __restrict__ binStart,
        const unsigned short* __restrict__ hin,
        const void* __restrict__ Wl, const void* __restrict__ bia,
        const void* __restrict__ Wr, const int* __restrict__ flags,
        float* __restrict__ h3, int n, int e) {
    __shared__ int ecol[GCAP];
    __shared__ float wl[NCLS][HID], wr[NCLS][HID], bb[NCLS];
    __shared__ float fbuf[HID][128];
    int t = threadIdx.x;
    int b = blockIdx.x;
    int isbf = flags[1];
    if (t < NCLS * HID) {
        wl[t >> 4][t & 15] = ldw(Wl, t, isbf);
        wr[t >> 4][t & 15] = ldw(Wr, t, isbf);
    }
    if (t < NCLS) bb[t] = ldw(bia, t, isbf);
    int s0 = binStart[b];
    int s1 = binStart[b + 1];
    int cnt = s1 - s0;
    int scnt = (cnt < GCAP) ? cnt : GCAP;
    for (int i = t; i < scnt; i += 256)
        ecol[i] = __builtin_nontemporal_load(col + s0 + i);
    __syncthreads();
    int nl = t >> 1;
    int j  = t & 1;
    int node = (b << SHIFT) + nl;
    if (node >= n) return;
    int lo = rowStart[node];
    int hi = (node + 1 < n) ? rowStart[node + 1] : e;
    const uint4* h4 = (const uint4*)hin;
    float a8[8];
    #pragma unroll
    for (int k = 0; k < 8; k++) a8[k] = 0.0f;
    for (int i = lo; i < hi; i++) {
        int idx = i - s0;
        int s = (idx < GCAP) ? ecol[idx] : col[i];
        uint4 v = h4[(size_t)s * 2 + j];
        float f[8];
        unp8(v, f);
        #pragma unroll
        for (int k = 0; k < 8; k++) a8[k] += f[k];
    }
    float invd = 1.0f / fmaxf((float)(hi - lo), 1.0f);
    #pragma unroll
    for (int k = 0; k < 8; k++) a8[k] *= invd;
    #pragma unroll
    for (int k = 0; k < 8; k++) fbuf[8 * j + k][nl] = a8[k];
    float a[HID];
    #pragma unroll
    for (int k = 0; k < HID; k++) a[k] = fbuf[k][nl];
    float hb[HID];
    unp8(h4[(size_t)node * 2], hb);
    unp8(h4[(size_t)node * 2 + 1], hb + 8);
    float o[NCLS]; float sq = 0.0f;
    #pragma unroll
    for (int f = 0; f < NCLS; f++) {
        float acc = bb[f];
        #pragma unroll
        for (int k = 0; k < HID; k++)
            acc += a[k] * wl[f][k] + hb[k] * wr[f][k];
        o[f] = acc;
        sq += acc * acc;
    }
    float inn = 1.0f / fmaxf(sqrtf(sq), 1e-12f);
    float* op = h3 + (size_t)node * NCLS;
    if (j == 0) {
        #pragma unroll
        for (int f = 0; f < 8; f++) op[f] = o[f] * inn;
    } else {
        op[8] = o[8] * inn;
        op[9] = o[9] * inn;
    }
}

// ---------------------------------------------------------------------------
// K5: per-graph mean pool (batch sorted -> binary search) + softmax.
__device__ __forceinline__ int lbound(const int* __restrict__ a, int n, int key, int sh) {
    int lo = 0, hi = n;
    while (lo < hi) {
        int mid = (lo + hi) >> 1;
        if (a[((size_t)mid) << sh] < key) lo = mid + 1; else hi = mid;
    }
    return lo;
}

__global__ void k_pool_softmax(const float* __restrict__ h3,
                               const int* __restrict__ batch,
                               const int* __restrict__ flags,
                               void* __restrict__ out, int n) {
    int g = blockIdx.x;
    int lane = threadIdx.x;
    int sh = flags[0];
    int lo = lbound(batch, n, g, sh);
    int hi = lbound(batch, n, g + 1, sh);
    float acc[NCLS];
    #pragma unroll
    for (int c = 0; c < NCLS; c++) acc[c] = 0.0f;
    for (int i = lo + lane; i < hi; i += 64) {
        const float* r = h3 + (size_t)i * NCLS;
        #pragma unroll
        for (int c = 0; c < NCLS; c++) acc[c] += r[c];
    }
    #pragma unroll
    for (int c = 0; c < NCLS; c++) {
        #pragma unroll
        for (int off = 1; off < 64; off <<= 1)
            acc[c] += __shfl_xor(acc[c], off);
    }
    float invc = 1.0f / fmaxf((float)(hi - lo), 1.0f);
    float m = -1e30f;
    #pragma unroll
    for (int c = 0; c < NCLS; c++) { acc[c] *= invc; m = fmaxf(m, acc[c]); }
    float s = 0.0f;
    #pragma unroll
    for (int c = 0; c < NCLS; c++) { acc[c] = expf(acc[c] - m); s += acc[c]; }
    float invs = 1.0f / s;
    if (lane < NCLS) {
        float v = acc[lane] * invs;
        size_t idx = (size_t)g * NCLS + lane;
        if (flags[1]) ((__hip_bfloat16*)out)[idx] = __float2bfloat16(v);
        else          ((float*)out)[idx] = v;
    }
}

// ---------------------------------------------------------------------------
extern "C" void kernel_launch(void* const* d_in, const int* in_sizes, int n_in,
                              void* d_out, int out_size, void* d_ws, size_t ws_size,
                              hipStream_t stream) {
    const void* x   = d_in[0];
    const int*  ei  = (const int*)d_in[1];
    const int*  bat = (const int*)d_in[2];
    const void* emb = d_in[3];
    const void* W1l = d_in[4];  const void* b1 = d_in[5];  const void* W1r = d_in[6];
    const void* W2l = d_in[7];  const void* b2 = d_in[8];  const void* W2r = d_in[9];
    const void* W3l = d_in[10]; const void* b3 = d_in[11]; const void* W3r = d_in[12];

    int n = in_sizes[0] / N_FEAT;
    int e = in_sizes[1] / 2;
    int nbins = (n + (1 << SHIFT) - 1) >> SHIFT;
    int nblk  = (e + CH - 1) / CH;

    // ws: hcur[16n] bf16 | hnext[16n] bf16 | h3[10n] f32 | col[e] |
    //     rowStart[n] | binCnt | binStart | rbBuf[nblk*nbins] | flags
    unsigned short* hcur  = (unsigned short*)d_ws;
    unsigned short* hnext = hcur + (size_t)n * HID;
    float* h3       = (float*)(hnext + (size_t)n * HID);
    int*   col      = (int*)(h3 + (size_t)n * NCLS);
    int*   rowStart = col + e;
    int*   binCnt   = rowStart + n;
    int*   binStart = binCnt + nbins;
    int*   rbBuf    = binStart + (nbins + 1);
    int*   flags    = rbBuf + (size_t)nblk * nbins;

    int ngrid4 = (n + 3) / 4;

    // probes + CSR build
    k_detect<<<1, 64, 0, stream>>>(ei, (const unsigned int*)x, flags);
    k_binhist<<<nblk, 256, 0, stream>>>(ei, flags, rbBuf, e, nbins);
    k_colscan<<<nbins, 1024, 0, stream>>>(rbBuf, binCnt, nblk, nbins);
    k_scanbins<<<1, 1024, 0, stream>>>(binCnt, binStart, nbins, e);
    k_binplace<<<nblk, 256, 0, stream>>>(ei, flags, binStart, rbBuf, col, e, nbins);
    k_place<<<nbins, 256, 0, stream>>>(col, binStart, rowStart, n, e);

    // initial embedding (bf16 h table)
    k_argmax_embed<<<ngrid4, 256, 0, stream>>>(x, emb, flags, hcur, n);

    // 3 gather+combine layers (bin-aligned blocks, LDS-staged col)
    k_gc <<<nbins, 256, 0, stream>>>(col, rowStart, binStart, hcur,  W1l, b1, W1r, flags, hnext, n, e);
    k_gc <<<nbins, 256, 0, stream>>>(col, rowStart, binStart, hnext, W2l, b2, W2r, flags, hcur,  n, e);
    k_gc3<<<nbins, 256, 0, stream>>>(col, rowStart, binStart, hcur,  W3l, b3, W3r, flags, h3,    n, e);

    // pool + softmax
    k_pool_softmax<<<NGRAPH, 64, 0, stream>>>(h3, bat, flags, d_out, n);
}